// Round 1
// baseline (2222.063 us; speedup 1.0000x reference)
//
#include <hip/hip_runtime.h>
#include <math.h>

#define B_ 4
#define T_ 1024
#define K_ 64
#define D_ 1024
#define V_ 32000
#define NT (B_*T_)   // 4096 tokens

// ---------------------------------------------------------------------------
// Kernel 1: per-token block.
//   pass 1: bandwidth = exp(q.Wb[0:D] + (1/K) * sum_k keys[k].Wb[D:2D] + bb)
//   softmax over K=64 distances (one wave)
//   scatter weights into probs (atomicAdd; each row owned by one block)
//   pass 2: wsk[d] = sum_k w[k]*keys[k][d]
// ---------------------------------------------------------------------------
__global__ __launch_bounds__(256) void k1_token(
    const float* __restrict__ query, const float* __restrict__ keys,
    const float* __restrict__ dist,  const int* __restrict__ vals,
    const float* __restrict__ Wb,    const float* __restrict__ bb,
    float* __restrict__ probs,       float* __restrict__ wsk)
{
  const int bid = blockIdx.x;      // token id in [0, NT)
  const int tid = threadIdx.x;     // 256 threads

  const float4* k4  = (const float4*)(keys + (size_t)bid * K_ * D_);
  const float4* q4  = (const float4*)(query + (size_t)bid * D_);
  const float4* wq4 = (const float4*)(Wb);        // first D
  const float4* wk4 = (const float4*)(Wb + D_);   // second D

  __shared__ float red[256];
  __shared__ float w_sh[K_];
  __shared__ float bw_sh;

  // ---- pass 1: keys . Wb_k (sum over k,d), plus q . Wb_q ----
  float acc = 0.f;
  // K_*D_/4 = 16384 float4 elements, 64 iters per thread
  for (int i = tid; i < K_ * D_ / 4; i += 256) {
    float4 kv = k4[i];
    float4 wv = wk4[i & (D_ / 4 - 1)];
    acc += kv.x * wv.x + kv.y * wv.y + kv.z * wv.z + kv.w * wv.w;
  }
  acc *= (1.0f / K_);
  {
    // D_/4 == 256 == blockDim.x: one float4 per thread
    float4 qv = q4[tid];
    float4 wv = wq4[tid];
    acc += qv.x * wv.x + qv.y * wv.y + qv.z * wv.z + qv.w * wv.w;
  }
  red[tid] = acc;
  __syncthreads();
  for (int s = 128; s > 0; s >>= 1) {
    if (tid < s) red[tid] += red[tid + s];
    __syncthreads();
  }
  if (tid == 0) bw_sh = expf(red[0] + bb[0]);
  __syncthreads();

  // ---- softmax over K=64 (single wave: threads 0..63) ----
  if (tid < 64) {
    float sc = -sqrtf(dist[(size_t)bid * K_ + tid]) / bw_sh;
    float m = sc;
    for (int off = 32; off > 0; off >>= 1) m = fmaxf(m, __shfl_xor(m, off));
    float e = expf(sc - m);
    float s = e;
    for (int off = 32; off > 0; off >>= 1) s += __shfl_xor(s, off);
    float w = e / s;
    w_sh[tid] = w;
    int v = vals[(size_t)bid * K_ + tid];
    atomicAdd(&probs[(size_t)bid * V_ + v], w);
  }
  __syncthreads();

  // ---- pass 2: weighted sum of keys ----
  float4 o = make_float4(0.f, 0.f, 0.f, 0.f);
#pragma unroll 8
  for (int k = 0; k < K_; ++k) {
    float w = w_sh[k];
    float4 kv = k4[k * (D_ / 4) + tid];
    o.x += w * kv.x; o.y += w * kv.y; o.z += w * kv.z; o.w += w * kv.w;
  }
  ((float4*)(wsk + (size_t)bid * D_))[tid] = o;
}

// ---------------------------------------------------------------------------
// Kernel 2: H = relu(concat(query, wsk) @ W1 + b1)
//   M=4096 tokens, Kdim=2048, N=1024.  64x64 tile, BK=32, 256 threads, 4x4/thread.
//   A tile: k0<1024 reads query, else wsk (BK divides 1024 so single source).
// ---------------------------------------------------------------------------
__global__ __launch_bounds__(256) void k2_mlp_gemm(
    const float* __restrict__ query, const float* __restrict__ wsk,
    const float* __restrict__ W1,    const float* __restrict__ b1,
    float* __restrict__ H)
{
  __shared__ float As[32][65];   // [kk][m], +1 pad
  __shared__ float Bs[32][64];   // [kk][n]

  const int tid = threadIdx.x;
  const int tx = tid & 15;       // n direction
  const int ty = tid >> 4;       // m direction
  const int m0 = blockIdx.y * 64;
  const int n0 = blockIdx.x * 64;

  float c[4][4];
#pragma unroll
  for (int i = 0; i < 4; ++i)
#pragma unroll
    for (int j = 0; j < 4; ++j) c[i][j] = 0.f;

  for (int k0 = 0; k0 < 2048; k0 += 32) {
    const float* src = (k0 < 1024) ? (query + k0) : (wsk + (k0 - 1024));
    // load A tile 64x32 (global coalesced along kk)
#pragma unroll
    for (int idx = tid; idx < 64 * 32; idx += 256) {
      int m = idx >> 5, kk = idx & 31;
      As[kk][m] = src[(size_t)(m0 + m) * 1024 + kk];
    }
    // load B tile 32x64 (global coalesced along n)
#pragma unroll
    for (int idx = tid; idx < 32 * 64; idx += 256) {
      int n = idx & 63, kk = idx >> 6;
      Bs[kk][n] = W1[(size_t)(k0 + kk) * 1024 + n0 + n];
    }
    __syncthreads();
#pragma unroll
    for (int kk = 0; kk < 32; ++kk) {
      float a[4], b[4];
#pragma unroll
      for (int i = 0; i < 4; ++i) a[i] = As[kk][ty * 4 + i];
#pragma unroll
      for (int j = 0; j < 4; ++j) b[j] = Bs[kk][tx * 4 + j];
#pragma unroll
      for (int i = 0; i < 4; ++i)
#pragma unroll
        for (int j = 0; j < 4; ++j) c[i][j] += a[i] * b[j];
    }
    __syncthreads();
  }

#pragma unroll
  for (int i = 0; i < 4; ++i) {
    int m = m0 + ty * 4 + i;
#pragma unroll
    for (int j = 0; j < 4; ++j) {
      int n = n0 + tx * 4 + j;
      float v = c[i][j] + b1[n];
      H[(size_t)m * 1024 + n] = v > 0.f ? v : 0.f;
    }
  }
}

// ---------------------------------------------------------------------------
// Kernel 3: lambda = sigmoid(H . W2 + b2), one block per token
// ---------------------------------------------------------------------------
__global__ __launch_bounds__(256) void k3_lambda(
    const float* __restrict__ H, const float* __restrict__ W2,
    const float* __restrict__ b2, float* __restrict__ lam)
{
  const int bid = blockIdx.x;
  const int tid = threadIdx.x;
  float4 h = ((const float4*)(H + (size_t)bid * D_))[tid];
  float4 w = ((const float4*)W2)[tid];
  float acc = h.x * w.x + h.y * w.y + h.z * w.z + h.w * w.w;
  __shared__ float red[256];
  red[tid] = acc;
  __syncthreads();
  for (int s = 128; s > 0; s >>= 1) {
    if (tid < s) red[tid] += red[tid + s];
    __syncthreads();
  }
  if (tid == 0) {
    float logit = red[0] + b2[0];
    lam[bid] = 1.f / (1.f + expf(-logit));
  }
}

extern "C" void kernel_launch(void* const* d_in, const int* in_sizes, int n_in,
                              void* d_out, int out_size, void* d_ws, size_t ws_size,
                              hipStream_t stream) {
  const float* query = (const float*)d_in[0];
  const float* keys  = (const float*)d_in[1];
  const float* dist  = (const float*)d_in[2];
  const int*   vals  = (const int*)d_in[3];
  const float* Wb    = (const float*)d_in[4];
  const float* bb    = (const float*)d_in[5];
  const float* W1    = (const float*)d_in[6];
  const float* b1    = (const float*)d_in[7];
  const float* W2    = (const float*)d_in[8];
  const float* b2    = (const float*)d_in[9];

  float* out   = (float*)d_out;
  float* probs = out;                        // [NT, V]
  float* lam   = out + (size_t)NT * V_;      // [NT]
  float* wsk   = (float*)d_ws;               // [NT, D] = 16 MB
  float* H     = wsk + (size_t)NT * D_;      // [NT, D] = 16 MB

  // zero the scatter target (harness poisons d_out each call)
  hipMemsetAsync(probs, 0, (size_t)NT * V_ * sizeof(float), stream);

  k1_token<<<NT, 256, 0, stream>>>(query, keys, dist, vals, Wb, bb, probs, wsk);
  k2_mlp_gemm<<<dim3(16, 64), 256, 0, stream>>>(query, wsk, W1, b1, H);
  k3_lambda<<<NT, 256, 0, stream>>>(H, W2, b2, lam);
}